// Round 5
// baseline (151.273 us; speedup 1.0000x reference)
//
#include <hip/hip_runtime.h>

#define BB 8
#define NN 1024
#define DM 256
#define HH 8
#define HD 32
#define TC 768   // 3*DM

typedef __bf16 bf16x8 __attribute__((ext_vector_type(8)));
typedef __bf16 bf16x4 __attribute__((ext_vector_type(4)));
typedef float  f32x4  __attribute__((ext_vector_type(4)));
typedef int    i32x4  __attribute__((ext_vector_type(4)));
typedef unsigned int u32;

// ---------------- precast: x -> bf16, W -> W^T bf16 ----------------
__global__ __launch_bounds__(256) void precast(
    const float* __restrict__ x, const float* __restrict__ W,
    __bf16* __restrict__ xb, __bf16* __restrict__ Wt)
{
  const int tid = threadIdx.x;
  const int bid = blockIdx.x;
  if (bid < 48) {
    __shared__ __bf16 T[64][65];
    const int ct = bid % 12, kt = bid / 12;
    const int c0 = ct * 64, k0 = kt * 64;
    #pragma unroll
    for (int i = 0; i < 16; ++i) {         // read coalesced along c
      int e = tid + i * 256, kk = e >> 6, cc = e & 63;
      T[cc][kk] = (__bf16)W[(size_t)(k0 + kk) * TC + c0 + cc];
    }
    __syncthreads();
    #pragma unroll
    for (int i = 0; i < 16; ++i) {         // write coalesced along k
      int e = tid + i * 256, cc = e >> 6, kk = e & 63;
      Wt[(size_t)(c0 + cc) * DM + k0 + kk] = T[cc][kk];
    }
  } else {
    const size_t e = (size_t)(bid - 48) * 256 + tid;   // float4 index
    const float4 v = ((const float4*)x)[e];
    bf16x4 o;
    o[0] = (__bf16)v.x; o[1] = (__bf16)v.y;
    o[2] = (__bf16)v.z; o[3] = (__bf16)v.w;
    ((bf16x4*)xb)[e] = o;
  }
}

// ---------------- QKV projection: global_load_lds + BK=64 ------------------
__global__ __launch_bounds__(256, 3) void qkv_gemm(
    const __bf16* __restrict__ xb, const __bf16* __restrict__ Wt,
    const float* __restrict__ bias, __bf16* __restrict__ Qb,
    __bf16* __restrict__ Kb, __bf16* __restrict__ Vt)
{
  __shared__ __align__(16) char LDSU[49152];
  __bf16* As0 = (__bf16*)LDSU;             // 16 KB
  __bf16* Bs0 = (__bf16*)(LDSU + 16384);   //  8 KB
  __bf16* As1 = (__bf16*)(LDSU + 24576);   // 16 KB
  __bf16* Bs1 = (__bf16*)(LDSU + 40960);   //  8 KB

  const int tid  = threadIdx.x;
  const int w    = tid >> 6, lane = tid & 63;
  const int n16  = lane & 15, quad = lane >> 4;
  const int m0   = blockIdx.y * 128, c0 = blockIdx.x * 64;
  const int bb   = m0 >> 10, n0 = m0 & 1023;

  const int stRow = w*8 + (lane >> 3);
  const int stG   = (lane & 7) ^ (lane >> 3);
  const __bf16* gA = &xb[(size_t)(m0 + stRow)*DM + stG*8];
  const __bf16* gB = &Wt[(size_t)(c0 + stRow)*DM + stG*8];

#define QKV_STAGE(Adst, Bdst, K0) do {                                        \
    _Pragma("unroll")                                                         \
    for (int i_ = 0; i_ < 4; ++i_) {                                          \
      const __bf16* gp_ = gA + (size_t)(i_*32)*DM + (K0);                     \
      __bf16* lp_ = (Adst) + (i_*32 + w*8)*64;                                \
      __builtin_amdgcn_global_load_lds(                                       \
          (const __attribute__((address_space(1))) u32*)gp_,                  \
          (__attribute__((address_space(3))) u32*)lp_, 16, 0, 0);             \
    }                                                                         \
    _Pragma("unroll")                                                         \
    for (int i_ = 0; i_ < 2; ++i_) {                                          \
      const __bf16* gp_ = gB + (size_t)(i_*32)*DM + (K0);                     \
      __bf16* lp_ = (Bdst) + (i_*32 + w*8)*64;                                \
      __builtin_amdgcn_global_load_lds(                                       \
          (const __attribute__((address_space(1))) u32*)gp_,                  \
          (__attribute__((address_space(3))) u32*)lp_, 16, 0, 0);             \
    }                                                                         \
  } while (0)

  f32x4 acc[2][4] = {};

  QKV_STAGE(As0, Bs0, 0);
  __syncthreads();

  #pragma unroll
  for (int kk = 0; kk < 4; ++kk) {
    __bf16* Ac = (kk & 1) ? As1 : As0;
    __bf16* Bc = (kk & 1) ? Bs1 : Bs0;
    if (kk == 0)      QKV_STAGE(As1, Bs1, 64);
    else if (kk == 1) QKV_STAGE(As0, Bs0, 128);
    else if (kk == 2) QKV_STAGE(As1, Bs1, 192);
    #pragma unroll
    for (int ks = 0; ks < 2; ++ks) {
      const int ch = ((ks*4 + quad) ^ (n16 & 7)) * 8;   // bf16 offset in row
      bf16x8 af0 = *(const bf16x8*)&Ac[(w*32 + n16)*64 + ch];
      bf16x8 af1 = *(const bf16x8*)&Ac[(w*32 + 16 + n16)*64 + ch];
      #pragma unroll
      for (int cb = 0; cb < 4; ++cb) {
        bf16x8 bfb = *(const bf16x8*)&Bc[(cb*16 + n16)*64 + ch];
        acc[0][cb] = __builtin_amdgcn_mfma_f32_16x16x32_bf16(af0, bfb, acc[0][cb], 0, 0, 0);
        acc[1][cb] = __builtin_amdgcn_mfma_f32_16x16x32_bf16(af1, bfb, acc[1][cb], 0, 0, 0);
      }
    }
    __syncthreads();
  }

  float bv[4];
  #pragma unroll
  for (int cb = 0; cb < 4; ++cb) bv[cb] = bias[c0 + cb*16 + n16];

  if (c0 < 512) {
    __bf16* Ct = (__bf16*)LDSU;
    #pragma unroll
    for (int cb = 0; cb < 4; ++cb)
      #pragma unroll
      for (int mb = 0; mb < 2; ++mb)
        #pragma unroll
        for (int r = 0; r < 4; ++r)
          Ct[(w*32 + mb*16 + quad*4 + r)*72 + cb*16 + n16] =
              (__bf16)(acc[mb][cb][r] + bv[cb]);
    __syncthreads();
    const int chunk = tid & 3, hh = (tid >> 2) & 1, rbase = tid >> 3;
    const int c_head = c0 + hh*32;
    const int h = (c_head >> 5) & 7;
    __bf16* base = (c_head >> 8) ? Kb : Qb;
    #pragma unroll
    for (int it = 0; it < 4; ++it) {
      int rl = rbase + it*32;
      bf16x8 v = *(const bf16x8*)&Ct[rl*72 + hh*32 + chunk*8];
      *(bf16x8*)&base[((size_t)((bb*HH + h)*NN + n0 + rl))*HD + chunk*8] = v;
    }
  } else {
    __bf16* CtT = (__bf16*)LDSU;
    #pragma unroll
    for (int cb = 0; cb < 4; ++cb)
      #pragma unroll
      for (int mb = 0; mb < 2; ++mb) {
        bf16x4 t;
        #pragma unroll
        for (int r = 0; r < 4; ++r) t[r] = (__bf16)(acc[mb][cb][r] + bv[cb]);
        *(bf16x4*)&CtT[(cb*16 + n16)*136 + w*32 + mb*16 + quad*4] = t;
      }
    __syncthreads();
    const int col = tid >> 2, sg = tid & 3;
    const int c = c0 + col;
    const int h = (c >> 5) & 7, dd = c & 31;
    __bf16* dst = &Vt[((size_t)((bb*HH + h)*HD + dd))*NN + n0 + sg*32];
    const __bf16* srcp = &CtT[col*136 + sg*32];
    #pragma unroll
    for (int q2 = 0; q2 < 4; ++q2)
      *(bf16x8*)&dst[q2*8] = *(const bf16x8*)&srcp[q2*8];
  }
}

// ---------------- fused moire attention (R14: register P, V-col permute) ---
// S^T = mfma(K, Q), K staged NATURALLY: lane (n16,quad) call c reg r holds
// S[q = w*16+n16][j = 16c + 4*quad + r].
//  -> adj: 4x float4/tile at col 16c+4*quad: per instr 16 rows x dense 64B ✓
//  -> mask: 4x int4/tile, coalesced.
// PV A-frag needs lane k-slot p = 8*quad+i, so V is stored COLUMN-PERMUTED:
//   physical col p holds V row j = (p&32) + 16*((p>>2)&1) + 4*((p>>3)&3) + (p&3)
// making pa[(c&1)*4+r] = exp(s-elem) lane-local. P never touches LDS.
// lacc/PV-output/epilogue row-ownership identical to R10 (verified mapping).
__global__ __launch_bounds__(256, 4) void attn_kernel(
    const __bf16* __restrict__ Q, const __bf16* __restrict__ K,
    const __bf16* __restrict__ Vt, const float* __restrict__ adj,
    const int* __restrict__ mask, const float* __restrict__ shifts,
    const float* __restrict__ widths, const float* __restrict__ slw,
    float* __restrict__ out)
{
  __shared__ __align__(16) __bf16 Ks[2][64][40];     // 10.0 KB double buf
  __shared__ __align__(16) __bf16 Vts[2][32][72];    //  9.0 KB double buf

  const int tid  = threadIdx.x;
  const int w    = tid >> 6, lane = tid & 63;
  const int n16  = lane & 15, quad = lane >> 4;
  const int bh   = blockIdx.x >> 4, qt = blockIdx.x & 15;   // natural order
  const int b    = bh >> 3, h = bh & 7;
  const int q0   = qt * 64;

  const float L2E   = 1.4426950408889634f;
  const float sh    = shifts[h];
  const float ninvw = -L2E / fmaxf(widths[h], 0.5f);
  const float slv   = slw[h] * L2E;
  const float scl   = 0.17677669529663687f * L2E;
  const float MASKV = -28.0f;   // constant: fully-masked rows stay uniform
  const float c1 = -2.0f * sh * ninvw;
  const float c2 = sh * sh * ninvw;

  const int srow = tid >> 2, sseg = tid & 3;   // K staging (natural rows)
  const int vd   = tid >> 3, vsg  = tid & 7;   // V staging
  const int vA   = (vsg & 4) << 3;             // 0 or 32 (j half)
  const int vq   = vsg & 3;                    // q-hat of physical cols

  const __bf16* Kg = K + (size_t)bh*NN*HD;
  const __bf16* Vg = Vt + (size_t)bh*HD*NN;

  // Q fragment (B-operand of S^T mfma): col n16 <-> q row w*16+n16
  const bf16x8 qf =
      *(const bf16x8*)&Q[((size_t)bh*NN + q0 + w*16 + n16)*HD + quad*8];

  {  // stage j-tile 0 into buffer 0 (K natural; V column-permuted)
    *(bf16x8*)&Ks[0][srow][sseg*8] = *(const bf16x8*)&Kg[srow*HD + sseg*8];
    *(bf16x4*)&Vts[0][vd][vsg*8]     = *(const bf16x4*)&Vg[(size_t)vd*NN + vA + 4*vq];
    *(bf16x4*)&Vts[0][vd][vsg*8 + 4] = *(const bf16x4*)&Vg[(size_t)vd*NN + vA + 16 + 4*vq];
  }

  const bool mqv = mask[b*NN + q0 + w*16 + n16] != 0;   // one q-row per lane

  // per-lane adj row pointer; load unit = float4 at col j0 + 16c + 4*quad
  const float* aqp = adj + ((size_t)(b*NN + q0 + w*16 + n16))*NN + 4*quad;
  const int*   mjp = mask + b*NN + 4*quad;

  // adj register double-buffer; preload tile 0
  f32x4 av[2][4];
  #pragma unroll
  for (int c = 0; c < 4; ++c) av[0][c] = *(const f32x4*)&aqp[16*c];

  const int dloc = w*16 + n16 - 4*quad;   // diag: 16c + r == dloc

  const f32x4 zero = {0.f, 0.f, 0.f, 0.f};
  f32x4 o0 = zero, o1 = zero, lacc = zero;
  bf16x8 onesb;
  #pragma unroll
  for (int i = 0; i < 8; ++i) onesb[i] = (__bf16)1.0f;

  __syncthreads();

  #pragma unroll 2
  for (int jtl = 0; jtl < 16; ++jtl) {
    const int cur = jtl & 1, nxt = cur ^ 1;
    const int j0  = jtl * 64;

    bf16x8 kn; bf16x4 vn0, vn1;
    if (jtl < 15) {   // prefetch next K/V tile + next adj tile into regs
      kn  = *(const bf16x8*)&Kg[(j0 + 64 + srow)*HD + sseg*8];
      vn0 = *(const bf16x4*)&Vg[(size_t)vd*NN + j0 + 64 + vA + 4*vq];
      vn1 = *(const bf16x4*)&Vg[(size_t)vd*NN + j0 + 64 + vA + 16 + 4*vq];
      #pragma unroll
      for (int c = 0; c < 4; ++c)
        av[nxt][c] = *(const f32x4*)&aqp[j0 + 64 + 16*c];
    }

    // current-tile j-masks (4 KB region, L1/L2-hot after first tiles)
    i32x4 mj[4];
    #pragma unroll
    for (int c = 0; c < 4; ++c) mj[c] = *(const i32x4*)&mjp[j0 + 16*c];

    // S^T: call c covers K rows 16c..16c+15 (natural)
    f32x4 s[4];
    #pragma unroll
    for (int c = 0; c < 4; ++c) {
      bf16x8 kf = *(const bf16x8*)&Ks[cur][c*16 + n16][quad*8];
      s[c] = __builtin_amdgcn_mfma_f32_16x16x32_bf16(kf, qf, zero, 0, 0, 0);
    }

    // issue V reads early (consumed after exp block; lgkm drained by then)
    bf16x8 b00 = *(const bf16x8*)&Vts[cur][n16][quad*8];
    bf16x8 b01 = *(const bf16x8*)&Vts[cur][n16][32 + quad*8];
    bf16x8 b10 = *(const bf16x8*)&Vts[cur][16 + n16][quad*8];
    bf16x8 b11 = *(const bf16x8*)&Vts[cur][16 + n16][32 + quad*8];

    const bool diagtile = (jtl == qt);   // uniform branch
    bf16x8 pa0, pa1;
    // first half (c = 0,1) -> pa0, start PV immediately
    #pragma unroll
    for (int c = 0; c < 2; ++c)
      #pragma unroll
      for (int r = 0; r < 4; ++r) {
        float ad  = av[cur][c][r];
        float mo  = fmaf(ad, fmaf(ad, ninvw, c1), c2);   // 2-FMA moire
        float val = fmaf(s[c][r], scl, mo);
        if (diagtile && (16*c + r == dloc)) val += slv;
        bool ok = mqv && (mj[c][r] != 0);
        val = ok ? val : MASKV;
        pa0[c*4 + r] = (__bf16)__builtin_amdgcn_exp2f(val);
      }
    o0   = __builtin_amdgcn_mfma_f32_16x16x32_bf16(pa0, b00, o0, 0, 0, 0);
    o1   = __builtin_amdgcn_mfma_f32_16x16x32_bf16(pa0, b10, o1, 0, 0, 0);
    lacc = __builtin_amdgcn_mfma_f32_16x16x32_bf16(pa0, onesb, lacc, 0, 0, 0);
    // second half (c = 2,3) -> pa1
    #pragma unroll
    for (int c = 2; c < 4; ++c)
      #pragma unroll
      for (int r = 0; r < 4; ++r) {
        float ad  = av[cur][c][r];
        float mo  = fmaf(ad, fmaf(ad, ninvw, c1), c2);
        float val = fmaf(s[c][r], scl, mo);
        if (diagtile && (16*c + r == dloc)) val += slv;
        bool ok = mqv && (mj[c][r] != 0);
        val = ok ? val : MASKV;
        pa1[(c & 1)*4 + r] = (__bf16)__builtin_amdgcn_exp2f(val);
      }
    o0   = __builtin_amdgcn_mfma_f32_16x16x32_bf16(pa1, b01, o0, 0, 0, 0);
    o1   = __builtin_amdgcn_mfma_f32_16x16x32_bf16(pa1, b11, o1, 0, 0, 0);
    lacc = __builtin_amdgcn_mfma_f32_16x16x32_bf16(pa1, onesb, lacc, 0, 0, 0);

    if (jtl < 15) {
      *(bf16x8*)&Ks[nxt][srow][sseg*8]     = kn;
      *(bf16x4*)&Vts[nxt][vd][vsg*8]       = vn0;
      *(bf16x4*)&Vts[nxt][vd][vsg*8 + 4]   = vn1;
    }
    __syncthreads();   // single barrier per j-tile
  }

  #pragma unroll
  for (int r = 0; r < 4; ++r) {
    const float invl = 1.0f / lacc[r];
    const int n = q0 + w*16 + quad*4 + r;
    float* og = out + ((size_t)(b*NN + n))*DM + h*HD;
    og[n16]      = o0[r] * invl;
    og[16 + n16] = o1[r] * invl;
  }
}

extern "C" void kernel_launch(void* const* d_in, const int* in_sizes, int n_in,
                              void* d_out, int out_size, void* d_ws, size_t ws_size,
                              hipStream_t stream) {
  const float* x      = (const float*)d_in[0];
  const float* adj    = (const float*)d_in[1];
  const int*   mask   = (const int*)d_in[2];
  const float* W      = (const float*)d_in[3];
  const float* bias   = (const float*)d_in[4];
  const float* shifts = (const float*)d_in[5];
  const float* widths = (const float*)d_in[6];
  const float* slwp   = (const float*)d_in[7];
  float* out = (float*)d_out;

  const size_t BHND = (size_t)BB*HH*NN*HD;          // 2,097,152
  const size_t WTN  = (size_t)TC*DM;                // 196,608
  __bf16* xbuf = (__bf16*)d_ws;                      // [8192,256] bf16
  __bf16* Wt   = xbuf + BHND;                        // [768,256] bf16
  __bf16* Qb   = Wt + WTN;                           // [B,H,N,32]
  __bf16* Kb   = Qb + BHND;
  __bf16* Vt   = Kb + BHND;

  precast<<<dim3(48 + (int)(BHND/4/256)), 256, 0, stream>>>(x, W, xbuf, Wt);
  qkv_gemm<<<dim3(TC/64, (BB*NN)/128), 256, 0, stream>>>(xbuf, Wt, bias, Qb, Kb, Vt);
  attn_kernel<<<dim3(BB*HH*16), 256, 0, stream>>>(Qb, Kb, Vt, adj, mask,
                                                  shifts, widths, slwp, out);
}

// Round 6
// 140.446 us; speedup vs baseline: 1.0771x; 1.0771x over previous
//
#include <hip/hip_runtime.h>

#define BB 8
#define NN 1024
#define DM 256
#define HH 8
#define HD 32
#define TC 768   // 3*DM

typedef __bf16 bf16x8 __attribute__((ext_vector_type(8)));
typedef __bf16 bf16x4 __attribute__((ext_vector_type(4)));
typedef float  f32x4  __attribute__((ext_vector_type(4)));
typedef unsigned int u32;

// ---------------- precast: x -> bf16, W -> W^T bf16 ----------------
__global__ __launch_bounds__(256) void precast(
    const float* __restrict__ x, const float* __restrict__ W,
    __bf16* __restrict__ xb, __bf16* __restrict__ Wt)
{
  const int tid = threadIdx.x;
  const int bid = blockIdx.x;
  if (bid < 48) {
    __shared__ __bf16 T[64][65];
    const int ct = bid % 12, kt = bid / 12;
    const int c0 = ct * 64, k0 = kt * 64;
    #pragma unroll
    for (int i = 0; i < 16; ++i) {         // read coalesced along c
      int e = tid + i * 256, kk = e >> 6, cc = e & 63;
      T[cc][kk] = (__bf16)W[(size_t)(k0 + kk) * TC + c0 + cc];
    }
    __syncthreads();
    #pragma unroll
    for (int i = 0; i < 16; ++i) {         // write coalesced along k
      int e = tid + i * 256, cc = e >> 6, kk = e & 63;
      Wt[(size_t)(c0 + cc) * DM + k0 + kk] = T[cc][kk];
    }
  } else {
    const size_t e = (size_t)(bid - 48) * 256 + tid;   // float4 index
    const float4 v = ((const float4*)x)[e];
    bf16x4 o;
    o[0] = (__bf16)v.x; o[1] = (__bf16)v.y;
    o[2] = (__bf16)v.z; o[3] = (__bf16)v.w;
    ((bf16x4*)xb)[e] = o;
  }
}

// ---------------- QKV projection: global_load_lds + BK=64 ------------------
__global__ __launch_bounds__(256, 3) void qkv_gemm(
    const __bf16* __restrict__ xb, const __bf16* __restrict__ Wt,
    const float* __restrict__ bias, __bf16* __restrict__ Qb,
    __bf16* __restrict__ Kb, __bf16* __restrict__ Vt)
{
  __shared__ __align__(16) char LDSU[49152];
  __bf16* As0 = (__bf16*)LDSU;             // 16 KB
  __bf16* Bs0 = (__bf16*)(LDSU + 16384);   //  8 KB
  __bf16* As1 = (__bf16*)(LDSU + 24576);   // 16 KB
  __bf16* Bs1 = (__bf16*)(LDSU + 40960);   //  8 KB

  const int tid  = threadIdx.x;
  const int w    = tid >> 6, lane = tid & 63;
  const int n16  = lane & 15, quad = lane >> 4;
  const int m0   = blockIdx.y * 128, c0 = blockIdx.x * 64;
  const int bb   = m0 >> 10, n0 = m0 & 1023;

  const int stRow = w*8 + (lane >> 3);
  const int stG   = (lane & 7) ^ (lane >> 3);
  const __bf16* gA = &xb[(size_t)(m0 + stRow)*DM + stG*8];
  const __bf16* gB = &Wt[(size_t)(c0 + stRow)*DM + stG*8];

#define QKV_STAGE(Adst, Bdst, K0) do {                                        \
    _Pragma("unroll")                                                         \
    for (int i_ = 0; i_ < 4; ++i_) {                                          \
      const __bf16* gp_ = gA + (size_t)(i_*32)*DM + (K0);                     \
      __bf16* lp_ = (Adst) + (i_*32 + w*8)*64;                                \
      __builtin_amdgcn_global_load_lds(                                       \
          (const __attribute__((address_space(1))) u32*)gp_,                  \
          (__attribute__((address_space(3))) u32*)lp_, 16, 0, 0);             \
    }                                                                         \
    _Pragma("unroll")                                                         \
    for (int i_ = 0; i_ < 2; ++i_) {                                          \
      const __bf16* gp_ = gB + (size_t)(i_*32)*DM + (K0);                     \
      __bf16* lp_ = (Bdst) + (i_*32 + w*8)*64;                                \
      __builtin_amdgcn_global_load_lds(                                       \
          (const __attribute__((address_space(1))) u32*)gp_,                  \
          (__attribute__((address_space(3))) u32*)lp_, 16, 0, 0);             \
    }                                                                         \
  } while (0)

  f32x4 acc[2][4] = {};

  QKV_STAGE(As0, Bs0, 0);
  __syncthreads();

  #pragma unroll
  for (int kk = 0; kk < 4; ++kk) {
    __bf16* Ac = (kk & 1) ? As1 : As0;
    __bf16* Bc = (kk & 1) ? Bs1 : Bs0;
    if (kk == 0)      QKV_STAGE(As1, Bs1, 64);
    else if (kk == 1) QKV_STAGE(As0, Bs0, 128);
    else if (kk == 2) QKV_STAGE(As1, Bs1, 192);
    #pragma unroll
    for (int ks = 0; ks < 2; ++ks) {
      const int ch = ((ks*4 + quad) ^ (n16 & 7)) * 8;   // bf16 offset in row
      bf16x8 af0 = *(const bf16x8*)&Ac[(w*32 + n16)*64 + ch];
      bf16x8 af1 = *(const bf16x8*)&Ac[(w*32 + 16 + n16)*64 + ch];
      #pragma unroll
      for (int cb = 0; cb < 4; ++cb) {
        bf16x8 bfb = *(const bf16x8*)&Bc[(cb*16 + n16)*64 + ch];
        acc[0][cb] = __builtin_amdgcn_mfma_f32_16x16x32_bf16(af0, bfb, acc[0][cb], 0, 0, 0);
        acc[1][cb] = __builtin_amdgcn_mfma_f32_16x16x32_bf16(af1, bfb, acc[1][cb], 0, 0, 0);
      }
    }
    __syncthreads();
  }

  float bv[4];
  #pragma unroll
  for (int cb = 0; cb < 4; ++cb) bv[cb] = bias[c0 + cb*16 + n16];

  if (c0 < 512) {
    __bf16* Ct = (__bf16*)LDSU;
    #pragma unroll
    for (int cb = 0; cb < 4; ++cb)
      #pragma unroll
      for (int mb = 0; mb < 2; ++mb)
        #pragma unroll
        for (int r = 0; r < 4; ++r)
          Ct[(w*32 + mb*16 + quad*4 + r)*72 + cb*16 + n16] =
              (__bf16)(acc[mb][cb][r] + bv[cb]);
    __syncthreads();
    const int chunk = tid & 3, hh = (tid >> 2) & 1, rbase = tid >> 3;
    const int c_head = c0 + hh*32;
    const int h = (c_head >> 5) & 7;
    __bf16* base = (c_head >> 8) ? Kb : Qb;
    #pragma unroll
    for (int it = 0; it < 4; ++it) {
      int rl = rbase + it*32;
      bf16x8 v = *(const bf16x8*)&Ct[rl*72 + hh*32 + chunk*8];
      *(bf16x8*)&base[((size_t)((bb*HH + h)*NN + n0 + rl))*HD + chunk*8] = v;
    }
  } else {
    __bf16* CtT = (__bf16*)LDSU;
    #pragma unroll
    for (int cb = 0; cb < 4; ++cb)
      #pragma unroll
      for (int mb = 0; mb < 2; ++mb) {
        bf16x4 t;
        #pragma unroll
        for (int r = 0; r < 4; ++r) t[r] = (__bf16)(acc[mb][cb][r] + bv[cb]);
        *(bf16x4*)&CtT[(cb*16 + n16)*136 + w*32 + mb*16 + quad*4] = t;
      }
    __syncthreads();
    const int col = tid >> 2, sg = tid & 3;
    const int c = c0 + col;
    const int h = (c >> 5) & 7, dd = c & 31;
    __bf16* dst = &Vt[((size_t)((bb*HH + h)*HD + dd))*NN + n0 + sg*32];
    const __bf16* srcp = &CtT[col*136 + sg*32];
    #pragma unroll
    for (int q2 = 0; q2 < 4; ++q2)
      *(bf16x8*)&dst[q2*8] = *(const bf16x8*)&srcp[q2*8];
  }
}

// ---------------- fused moire attention (R15: head-fused blocks) -----------
// block = (b, 32-q-row tile, head-group of 4); wave w = head hg*4+w.
// adj tile [32 q][64 j] staged ONCE in LDS (f32, double-buf) and shared by
// all 4 heads: adj VMEM traffic /4 (was 8 re-reads per pass, the latency-
// bound L3 stream). K/V/Ps are per-wave private LDS (single-buffered;
// within-wave ds-in-order makes read->overwrite safe without a barrier).
// ONE barrier per j-tile (for the shared As only). Inner math = R10-proven:
// s[cb][r] = S[q=g*16+quad*4+r][j=cb*16+n16], Ps round-trip, PV, lacc-MFMA.
__global__ __launch_bounds__(256, 2) void attn_kernel(
    const __bf16* __restrict__ Q, const __bf16* __restrict__ K,
    const __bf16* __restrict__ Vt, const float* __restrict__ adj,
    const int* __restrict__ mask, const float* __restrict__ shifts,
    const float* __restrict__ widths, const float* __restrict__ slw,
    float* __restrict__ out)
{
  __shared__ __align__(16) __bf16 Ks[4][64][40];   // 20 KB per-head K tiles
  __shared__ __align__(16) __bf16 Vts[4][32][72];  // 18 KB per-head V tiles
  __shared__ __align__(16) float  As[2][32][68];   // 17 KB shared adj (dbuf)
  __shared__ __align__(16) __bf16 Ps[4][16][72];   //  9 KB per-wave P scratch

  const int tid  = threadIdx.x;
  const int w    = tid >> 6, lane = tid & 63;
  const int n16  = lane & 15, quad = lane >> 4;
  const int hg   = blockIdx.x & 1;
  const int qt   = (blockIdx.x >> 1) & 31;
  const int b    = blockIdx.x >> 6;
  const int h    = hg*4 + w;
  const int bh   = b*HH + h;
  const int q0   = qt * 32;

  const float L2E   = 1.4426950408889634f;
  const float sh    = shifts[h];
  const float ninvw = -L2E / fmaxf(widths[h], 0.5f);
  const float slv   = slw[h] * L2E;
  const float scl   = 0.17677669529663687f * L2E;
  const float MASKV = -28.0f;
  const float c1 = -2.0f * sh * ninvw;
  const float c2 = sh * sh * ninvw;

  const __bf16* Kg = K + (size_t)bh*NN*HD;
  const __bf16* Vg = Vt + (size_t)bh*HD*NN;

  // staging geometry (per wave for its own head; adj block-cooperative)
  const __bf16* kgp = Kg + (size_t)lane*HD;          // K row j0+lane, 4x16B
  const int vdr = lane >> 1, vc0 = (lane & 1)*32;    // V row d=vdr, 4x16B
  const __bf16* vgp = Vg + (size_t)vdr*NN + vc0;
  const int arow = tid >> 3, ac = (tid & 7)*4;       // adj row q0+arow
  const float* agp = adj + ((size_t)(b*NN + q0 + arow))*NN + ac;
  const int* mjp = mask + b*NN + n16;

  // q-side invariants
  const bf16x8 qf0 = *(const bf16x8*)&Q[((size_t)bh*NN + q0 +      n16)*HD + quad*8];
  const bf16x8 qf1 = *(const bf16x8*)&Q[((size_t)bh*NN + q0 + 16 + n16)*HD + quad*8];
  int mq[2][4];
  #pragma unroll
  for (int g = 0; g < 2; ++g)
    #pragma unroll
    for (int r = 0; r < 4; ++r)
      mq[g][r] = mask[b*NN + q0 + g*16 + quad*4 + r];

  // ---- stage tile 0 ----
  {
    bf16x8 k0[4], v0[4]; f32x4 aa, ab;
    #pragma unroll
    for (int c = 0; c < 4; ++c) k0[c] = *(const bf16x8*)&kgp[c*8];
    #pragma unroll
    for (int i = 0; i < 4; ++i) v0[i] = *(const bf16x8*)&vgp[i*8];
    aa = *(const f32x4*)&agp[0]; ab = *(const f32x4*)&agp[32];
    #pragma unroll
    for (int c = 0; c < 4; ++c) *(bf16x8*)&Ks[w][lane][c*8] = k0[c];
    #pragma unroll
    for (int i = 0; i < 4; ++i) *(bf16x8*)&Vts[w][vdr][vc0 + i*8] = v0[i];
    *(f32x4*)&As[0][arow][ac]      = aa;
    *(f32x4*)&As[0][arow][32 + ac] = ab;
  }
  int mj[4];
  #pragma unroll
  for (int cb = 0; cb < 4; ++cb) mj[cb] = mjp[cb*16];

  const f32x4 zero = {0.f, 0.f, 0.f, 0.f};
  f32x4 o0[2] = {zero, zero}, o1[2] = {zero, zero}, lacc[2] = {zero, zero};
  bf16x8 onesb;
  #pragma unroll
  for (int i = 0; i < 8; ++i) onesb[i] = (__bf16)1.0f;

  const int diagT = qt >> 1;          // j-tile containing the diagonal
  const int dbase = (qt & 1) * 32;    // j-local base of this q-tile

  __syncthreads();

  for (int jtl = 0; jtl < 16; ++jtl) {
    const int cur = jtl & 1;
    const int j0  = jtl * 64;

    // prefetch next tile into registers (latency hidden under compute)
    bf16x8 kn[4], vn[4]; f32x4 an0, an1; int mjn[4];
    if (jtl < 15) {
      #pragma unroll
      for (int c = 0; c < 4; ++c) kn[c] = *(const bf16x8*)&kgp[(size_t)(j0+64)*HD + c*8];
      #pragma unroll
      for (int i = 0; i < 4; ++i) vn[i] = *(const bf16x8*)&vgp[j0 + 64 + i*8];
      an0 = *(const f32x4*)&agp[j0 + 64];
      an1 = *(const f32x4*)&agp[j0 + 96];
      #pragma unroll
      for (int cb = 0; cb < 4; ++cb) mjn[cb] = mjp[j0 + 64 + cb*16];
    }

    // V fragments once per tile (shared by both q-groups)
    bf16x8 b00 = *(const bf16x8*)&Vts[w][n16][quad*8];
    bf16x8 b01 = *(const bf16x8*)&Vts[w][n16][32 + quad*8];
    bf16x8 b10 = *(const bf16x8*)&Vts[w][16 + n16][quad*8];
    bf16x8 b11 = *(const bf16x8*)&Vts[w][16 + n16][32 + quad*8];

    const bool diagtile = (jtl == diagT);

    #pragma unroll
    for (int g = 0; g < 2; ++g) {
      const bf16x8 qf = g ? qf1 : qf0;
      f32x4 s[4];
      #pragma unroll
      for (int cb = 0; cb < 4; ++cb) {
        bf16x8 kf = *(const bf16x8*)&Ks[w][cb*16 + n16][quad*8];
        s[cb] = __builtin_amdgcn_mfma_f32_16x16x32_bf16(qf, kf, zero, 0, 0, 0);
      }
      const int dref = dbase + g*16 + quad*4;   // diag: cb*16+n16 == dref+r
      #pragma unroll
      for (int r = 0; r < 4; ++r) {
        #pragma unroll
        for (int cb = 0; cb < 4; ++cb) {
          float a   = As[cur][g*16 + quad*4 + r][cb*16 + n16];
          float mo  = fmaf(a, fmaf(a, ninvw, c1), c2);   // 2-FMA moire
          float val = fmaf(s[cb][r], scl, mo);
          if (diagtile && (cb*16 + n16 == dref + r)) val += slv;
          bool ok = (mq[g][r] != 0) && (mj[cb] != 0);
          val = ok ? val : MASKV;
          Ps[w][quad*4 + r][cb*16 + n16] = (__bf16)__builtin_amdgcn_exp2f(val);
        }
      }
      bf16x8 a0 = *(const bf16x8*)&Ps[w][n16][quad*8];
      bf16x8 a1 = *(const bf16x8*)&Ps[w][n16][32 + quad*8];
      o0[g]   = __builtin_amdgcn_mfma_f32_16x16x32_bf16(a0, b00, o0[g], 0, 0, 0);
      o0[g]   = __builtin_amdgcn_mfma_f32_16x16x32_bf16(a1, b01, o0[g], 0, 0, 0);
      o1[g]   = __builtin_amdgcn_mfma_f32_16x16x32_bf16(a0, b10, o1[g], 0, 0, 0);
      o1[g]   = __builtin_amdgcn_mfma_f32_16x16x32_bf16(a1, b11, o1[g], 0, 0, 0);
      lacc[g] = __builtin_amdgcn_mfma_f32_16x16x32_bf16(a0, onesb, lacc[g], 0, 0, 0);
      lacc[g] = __builtin_amdgcn_mfma_f32_16x16x32_bf16(a1, onesb, lacc[g], 0, 0, 0);
    }

    if (jtl < 15) {   // stage next tile (K/V within-wave safe; As to other buf)
      #pragma unroll
      for (int c = 0; c < 4; ++c) *(bf16x8*)&Ks[w][lane][c*8] = kn[c];
      #pragma unroll
      for (int i = 0; i < 4; ++i) *(bf16x8*)&Vts[w][vdr][vc0 + i*8] = vn[i];
      *(f32x4*)&As[1 - cur][arow][ac]      = an0;
      *(f32x4*)&As[1 - cur][arow][32 + ac] = an1;
      #pragma unroll
      for (int cb = 0; cb < 4; ++cb) mj[cb] = mjn[cb];
    }
    __syncthreads();   // single barrier per j-tile (As producer/consumer)
  }

  #pragma unroll
  for (int g = 0; g < 2; ++g)
    #pragma unroll
    for (int r = 0; r < 4; ++r) {
      const float invl = 1.0f / lacc[g][r];
      const int n = q0 + g*16 + quad*4 + r;
      float* og = out + ((size_t)(b*NN + n))*DM + h*HD;
      og[n16]      = o0[g][r] * invl;
      og[16 + n16] = o1[g][r] * invl;
    }
}

extern "C" void kernel_launch(void* const* d_in, const int* in_sizes, int n_in,
                              void* d_out, int out_size, void* d_ws, size_t ws_size,
                              hipStream_t stream) {
  const float* x      = (const float*)d_in[0];
  const float* adj    = (const float*)d_in[1];
  const int*   mask   = (const int*)d_in[2];
  const float* W      = (const float*)d_in[3];
  const float* bias   = (const float*)d_in[4];
  const float* shifts = (const float*)d_in[5];
  const float* widths = (const float*)d_in[6];
  const float* slwp   = (const float*)d_in[7];
  float* out = (float*)d_out;

  const size_t BHND = (size_t)BB*HH*NN*HD;          // 2,097,152
  const size_t WTN  = (size_t)TC*DM;                // 196,608
  __bf16* xbuf = (__bf16*)d_ws;                      // [8192,256] bf16
  __bf16* Wt   = xbuf + BHND;                        // [768,256] bf16
  __bf16* Qb   = Wt + WTN;                           // [B,H,N,32]
  __bf16* Kb   = Qb + BHND;
  __bf16* Vt   = Kb + BHND;

  precast<<<dim3(48 + (int)(BHND/4/256)), 256, 0, stream>>>(x, W, xbuf, Wt);
  qkv_gemm<<<dim3(TC/64, (BB*NN)/128), 256, 0, stream>>>(xbuf, Wt, bias, Qb, Kb, Vt);
  attn_kernel<<<dim3(BB*32*2), 256, 0, stream>>>(Qb, Kb, Vt, adj, mask,
                                                 shifts, widths, slwp, out);
}

// Round 7
// 137.887 us; speedup vs baseline: 1.0971x; 1.0186x over previous
//
#include <hip/hip_runtime.h>

#define BB 8
#define NN 1024
#define DM 256
#define HH 8
#define HD 32
#define TC 768   // 3*DM

typedef __bf16 bf16x8 __attribute__((ext_vector_type(8)));
typedef __bf16 bf16x4 __attribute__((ext_vector_type(4)));
typedef float  f32x4  __attribute__((ext_vector_type(4)));
typedef unsigned int u32;

// ---------------- precast: x -> bf16, W -> W^T bf16 ----------------
__global__ __launch_bounds__(256) void precast(
    const float* __restrict__ x, const float* __restrict__ W,
    __bf16* __restrict__ xb, __bf16* __restrict__ Wt)
{
  const int tid = threadIdx.x;
  const int bid = blockIdx.x;
  if (bid < 48) {
    __shared__ __bf16 T[64][65];
    const int ct = bid % 12, kt = bid / 12;
    const int c0 = ct * 64, k0 = kt * 64;
    #pragma unroll
    for (int i = 0; i < 16; ++i) {         // read coalesced along c
      int e = tid + i * 256, kk = e >> 6, cc = e & 63;
      T[cc][kk] = (__bf16)W[(size_t)(k0 + kk) * TC + c0 + cc];
    }
    __syncthreads();
    #pragma unroll
    for (int i = 0; i < 16; ++i) {         // write coalesced along k
      int e = tid + i * 256, cc = e >> 6, kk = e & 63;
      Wt[(size_t)(c0 + cc) * DM + k0 + kk] = T[cc][kk];
    }
  } else {
    const size_t e = (size_t)(bid - 48) * 256 + tid;   // float4 index
    const float4 v = ((const float4*)x)[e];
    bf16x4 o;
    o[0] = (__bf16)v.x; o[1] = (__bf16)v.y;
    o[2] = (__bf16)v.z; o[3] = (__bf16)v.w;
    ((bf16x4*)xb)[e] = o;
  }
}

// ---------------- QKV projection: global_load_lds + BK=64 ------------------
__global__ __launch_bounds__(256, 3) void qkv_gemm(
    const __bf16* __restrict__ xb, const __bf16* __restrict__ Wt,
    const float* __restrict__ bias, __bf16* __restrict__ Qb,
    __bf16* __restrict__ Kb, __bf16* __restrict__ Vt)
{
  __shared__ __align__(16) char LDSU[49152];
  __bf16* As0 = (__bf16*)LDSU;             // 16 KB
  __bf16* Bs0 = (__bf16*)(LDSU + 16384);   //  8 KB
  __bf16* As1 = (__bf16*)(LDSU + 24576);   // 16 KB
  __bf16* Bs1 = (__bf16*)(LDSU + 40960);   //  8 KB

  const int tid  = threadIdx.x;
  const int w    = tid >> 6, lane = tid & 63;
  const int n16  = lane & 15, quad = lane >> 4;
  const int m0   = blockIdx.y * 128, c0 = blockIdx.x * 64;
  const int bb   = m0 >> 10, n0 = m0 & 1023;

  const int stRow = w*8 + (lane >> 3);
  const int stG   = (lane & 7) ^ (lane >> 3);
  const __bf16* gA = &xb[(size_t)(m0 + stRow)*DM + stG*8];
  const __bf16* gB = &Wt[(size_t)(c0 + stRow)*DM + stG*8];

#define QKV_STAGE(Adst, Bdst, K0) do {                                        \
    _Pragma("unroll")                                                         \
    for (int i_ = 0; i_ < 4; ++i_) {                                          \
      const __bf16* gp_ = gA + (size_t)(i_*32)*DM + (K0);                     \
      __bf16* lp_ = (Adst) + (i_*32 + w*8)*64;                                \
      __builtin_amdgcn_global_load_lds(                                       \
          (const __attribute__((address_space(1))) u32*)gp_,                  \
          (__attribute__((address_space(3))) u32*)lp_, 16, 0, 0);             \
    }                                                                         \
    _Pragma("unroll")                                                         \
    for (int i_ = 0; i_ < 2; ++i_) {                                          \
      const __bf16* gp_ = gB + (size_t)(i_*32)*DM + (K0);                     \
      __bf16* lp_ = (Bdst) + (i_*32 + w*8)*64;                                \
      __builtin_amdgcn_global_load_lds(                                       \
          (const __attribute__((address_space(1))) u32*)gp_,                  \
          (__attribute__((address_space(3))) u32*)lp_, 16, 0, 0);             \
    }                                                                         \
  } while (0)

  f32x4 acc[2][4] = {};

  QKV_STAGE(As0, Bs0, 0);
  __syncthreads();

  #pragma unroll
  for (int kk = 0; kk < 4; ++kk) {
    __bf16* Ac = (kk & 1) ? As1 : As0;
    __bf16* Bc = (kk & 1) ? Bs1 : Bs0;
    if (kk == 0)      QKV_STAGE(As1, Bs1, 64);
    else if (kk == 1) QKV_STAGE(As0, Bs0, 128);
    else if (kk == 2) QKV_STAGE(As1, Bs1, 192);
    #pragma unroll
    for (int ks = 0; ks < 2; ++ks) {
      const int ch = ((ks*4 + quad) ^ (n16 & 7)) * 8;   // bf16 offset in row
      bf16x8 af0 = *(const bf16x8*)&Ac[(w*32 + n16)*64 + ch];
      bf16x8 af1 = *(const bf16x8*)&Ac[(w*32 + 16 + n16)*64 + ch];
      #pragma unroll
      for (int cb = 0; cb < 4; ++cb) {
        bf16x8 bfb = *(const bf16x8*)&Bc[(cb*16 + n16)*64 + ch];
        acc[0][cb] = __builtin_amdgcn_mfma_f32_16x16x32_bf16(af0, bfb, acc[0][cb], 0, 0, 0);
        acc[1][cb] = __builtin_amdgcn_mfma_f32_16x16x32_bf16(af1, bfb, acc[1][cb], 0, 0, 0);
      }
    }
    __syncthreads();
  }

  float bv[4];
  #pragma unroll
  for (int cb = 0; cb < 4; ++cb) bv[cb] = bias[c0 + cb*16 + n16];

  if (c0 < 512) {
    __bf16* Ct = (__bf16*)LDSU;
    #pragma unroll
    for (int cb = 0; cb < 4; ++cb)
      #pragma unroll
      for (int mb = 0; mb < 2; ++mb)
        #pragma unroll
        for (int r = 0; r < 4; ++r)
          Ct[(w*32 + mb*16 + quad*4 + r)*72 + cb*16 + n16] =
              (__bf16)(acc[mb][cb][r] + bv[cb]);
    __syncthreads();
    const int chunk = tid & 3, hh = (tid >> 2) & 1, rbase = tid >> 3;
    const int c_head = c0 + hh*32;
    const int h = (c_head >> 5) & 7;
    __bf16* base = (c_head >> 8) ? Kb : Qb;
    #pragma unroll
    for (int it = 0; it < 4; ++it) {
      int rl = rbase + it*32;
      bf16x8 v = *(const bf16x8*)&Ct[rl*72 + hh*32 + chunk*8];
      *(bf16x8*)&base[((size_t)((bb*HH + h)*NN + n0 + rl))*HD + chunk*8] = v;
    }
  } else {
    __bf16* CtT = (__bf16*)LDSU;
    #pragma unroll
    for (int cb = 0; cb < 4; ++cb)
      #pragma unroll
      for (int mb = 0; mb < 2; ++mb) {
        bf16x4 t;
        #pragma unroll
        for (int r = 0; r < 4; ++r) t[r] = (__bf16)(acc[mb][cb][r] + bv[cb]);
        *(bf16x4*)&CtT[(cb*16 + n16)*136 + w*32 + mb*16 + quad*4] = t;
      }
    __syncthreads();
    const int col = tid >> 2, sg = tid & 3;
    const int c = c0 + col;
    const int h = (c >> 5) & 7, dd = c & 31;
    __bf16* dst = &Vt[((size_t)((bb*HH + h)*HD + dd))*NN + n0 + sg*32];
    const __bf16* srcp = &CtT[col*136 + sg*32];
    #pragma unroll
    for (int q2 = 0; q2 < 4; ++q2)
      *(bf16x8*)&dst[q2*8] = *(const bf16x8*)&srcp[q2*8];
  }
}

// ---------------- fused moire attention (R16: 2048 blocks, j-split waves) --
// block = (bh, 32-q-row tile); 4 waves = 2 q-groups x 2 j-halves.
// Wave (qg, jh): 16 q-rows x j-half 32 per 64-j tile: 2 QK MFMA, 8 exp,
// 8 Ps b16 writes, 1 Ps b128 read, 3 PV/lacc MFMA, 8 adj scalar loads.
// Partial (o, l) over j-halves reduced once at the end via LDS.
// K/V staged by global_load_lds (1 dwordx4 instr each/tile, no VGPR trip),
// LDS linear + chunk swizzle on BOTH source and read side (rule #21):
//   K[64][32]: slot(r,s) = K[r][(s^(r&3))*8]; read chunk quad^(n16&3) -> 2/bank
//   V[32][64]: slot(r,s) = V[r][(s^(r&7))*8]; read chunk (jh*4+quad)^(n16&7) -> 2/bank
// LDS 20.5 KB -> 7 blocks/CU; __launch_bounds__(256,8) caps VGPR at 64
// -> up to 28 waves/CU (vs 16 grid-limited in R10). TLP replaces the
// dropped adj register double-buffer.
__global__ __launch_bounds__(256, 8) void attn_kernel(
    const __bf16* __restrict__ Q, const __bf16* __restrict__ K,
    const __bf16* __restrict__ Vt, const float* __restrict__ adj,
    const int* __restrict__ mask, const float* __restrict__ shifts,
    const float* __restrict__ widths, const float* __restrict__ slw,
    float* __restrict__ out)
{
  __shared__ __align__(16) __bf16 Ks[2][64][32];   // 8 KB, chunk-swizzled
  __shared__ __align__(16) __bf16 Vts[2][32][64];  // 8 KB, chunk-swizzled
  __shared__ __align__(16) __bf16 Ps[32][72];      // 4.5 KB (R10-style pad)

  const int tid  = threadIdx.x;
  const int w    = tid >> 6, lane = tid & 63;
  const int n16  = lane & 15, quad = lane >> 4;
  const int qg   = w >> 1, jh = w & 1;
  const int bh   = blockIdx.x >> 5, qt = blockIdx.x & 31;
  const int b    = bh >> 3, h = bh & 7;
  const int q0   = qt * 32;

  const float L2E   = 1.4426950408889634f;
  const float sh    = shifts[h];
  const float ninvw = -L2E / fmaxf(widths[h], 0.5f);
  const float slv   = slw[h] * L2E;
  const float scl   = 0.17677669529663687f * L2E;
  const float MASKV = -28.0f;
  const float c1 = -2.0f * sh * ninvw;
  const float c2 = sh * sh * ninvw;

  // staging geometry: one dwordx4 DMA per thread per tile for K and V
  const int srow = tid >> 2, sseg = tid & 3;       // K: row, 16B chunk
  const int vd   = tid >> 3, vsg  = tid & 7;       // V: row, 16B chunk
  const __bf16* Kg = K + (size_t)bh*NN*HD;
  const __bf16* Vg = Vt + (size_t)bh*HD*NN;
  const __bf16* ksrc = Kg + srow*HD + (sseg ^ (srow & 3))*8;   // inv-swizzled src
  const __bf16* vsrc = Vg + (size_t)vd*NN + (vsg ^ (vd & 7))*8;
  __bf16* kdst0 = &Ks[0][0][0] + tid*8;
  __bf16* kdst1 = &Ks[1][0][0] + tid*8;
  __bf16* vdst0 = &Vts[0][0][0] + tid*8;
  __bf16* vdst1 = &Vts[1][0][0] + tid*8;

#define GLDS(g, l) __builtin_amdgcn_global_load_lds(                          \
    (const __attribute__((address_space(1))) u32*)(g),                        \
    (__attribute__((address_space(3))) u32*)(l), 16, 0, 0)

  GLDS(ksrc, kdst0);           // stage j-tile 0 into buffer 0
  GLDS(vsrc, vdst0);

  // q-side invariants
  const bf16x8 qf =
      *(const bf16x8*)&Q[((size_t)bh*NN + q0 + qg*16 + n16)*HD + quad*8];
  int mq[4];
  #pragma unroll
  for (int r = 0; r < 4; ++r) mq[r] = mask[b*NN + q0 + qg*16 + quad*4 + r];

  // adj row pointers (4 rows per lane-quad, dense 64B per row per instr)
  const float* ar0 = adj + ((size_t)(b*NN + q0 + qg*16 + quad*4))*NN + jh*32 + n16;
  const float* ar1 = ar0 + NN;
  const float* ar2 = ar0 + 2*NN;
  const float* ar3 = ar0 + 3*NN;
  const int*   mrp = mask + b*NN + jh*32 + n16;

  // LDS read swizzle offsets (loop-invariant)
  const int kbc = (quad ^ (n16 & 3)) * 8;                 // K read chunk
  const int vbc = (((jh << 2) + quad) ^ (n16 & 7)) * 8;   // V read chunk

  const f32x4 zero = {0.f, 0.f, 0.f, 0.f};
  f32x4 o0 = zero, o1 = zero, lacc = zero;
  bf16x8 onesb;
  #pragma unroll
  for (int i = 0; i < 8; ++i) onesb[i] = (__bf16)1.0f;

  const bool mydiagH = (jh == (qt & 1));   // diag falls in this wave's j-half
  const int  dT  = qt >> 1;                // j-tile containing the diagonal
  const int  dlr = n16 - quad*4;           // diag hits reg r == dlr (if 0..3)

  __syncthreads();

  #pragma unroll 2
  for (int jtl = 0; jtl < 16; ++jtl) {
    const int cur = jtl & 1;
    const int j0  = jtl * 64;

    if (jtl < 15) {   // DMA next K/V tile into the other buffer
      const __bf16* kg = ksrc + (size_t)(j0 + 64)*HD;
      const __bf16* vg = vsrc + (j0 + 64);
      if (cur) { GLDS(kg, kdst0); GLDS(vg, vdst0); }
      else     { GLDS(kg, kdst1); GLDS(vg, vdst1); }
    }

    // adj + mask for THIS tile, issued early (cover under QK MFMA + exp)
    int mj[2];
    #pragma unroll
    for (int cb = 0; cb < 2; ++cb) mj[cb] = mrp[j0 + cb*16];
    float av[4][2];
    #pragma unroll
    for (int cb = 0; cb < 2; ++cb) {
      av[0][cb] = ar0[j0 + cb*16];
      av[1][cb] = ar1[j0 + cb*16];
      av[2][cb] = ar2[j0 + cb*16];
      av[3][cb] = ar3[j0 + cb*16];
    }

    // QK^T for this wave's j-half (2 MFMAs)
    f32x4 s[2];
    #pragma unroll
    for (int cb = 0; cb < 2; ++cb) {
      bf16x8 kf = *(const bf16x8*)&Ks[cur][jh*32 + cb*16 + n16][kbc];
      s[cb] = __builtin_amdgcn_mfma_f32_16x16x32_bf16(qf, kf, zero, 0, 0, 0);
    }
    bf16x8 b0 = *(const bf16x8*)&Vts[cur][n16][vbc];
    bf16x8 b1 = *(const bf16x8*)&Vts[cur][16 + n16][vbc];

    const bool diagt = mydiagH && (jtl == dT);
    #pragma unroll
    for (int r = 0; r < 4; ++r) {
      #pragma unroll
      for (int cb = 0; cb < 2; ++cb) {
        float a   = av[r][cb];
        float mo  = fmaf(a, fmaf(a, ninvw, c1), c2);   // 2-FMA moire
        float val = fmaf(s[cb][r], scl, mo);
        if (diagt && (cb == qg) && (dlr == r)) val += slv;
        bool ok = (mq[r] != 0) && (mj[cb] != 0);
        val = ok ? val : MASKV;
        Ps[qg*16 + quad*4 + r][jh*32 + cb*16 + n16] =
            (__bf16)__builtin_amdgcn_exp2f(val);
      }
    }

    bf16x8 a0 = *(const bf16x8*)&Ps[qg*16 + n16][jh*32 + quad*8];
    o0   = __builtin_amdgcn_mfma_f32_16x16x32_bf16(a0, b0, o0, 0, 0, 0);
    o1   = __builtin_amdgcn_mfma_f32_16x16x32_bf16(a0, b1, o1, 0, 0, 0);
    lacc = __builtin_amdgcn_mfma_f32_16x16x32_bf16(a0, onesb, lacc, 0, 0, 0);

    __syncthreads();   // single barrier per j-tile (drains DMA + Ks/Vts reads)
  }

  // cross-wave reduction over j-halves (reuse Ks region; loop fully barriered)
  float* red = (float*)&Ks[0][0][0];
  if (jh) {
    float* p = red + (size_t)(qg*64 + lane)*12;
    *(f32x4*)&p[0] = o0; *(f32x4*)&p[4] = o1; *(f32x4*)&p[8] = lacc;
  }
  __syncthreads();
  if (!jh) {
    const float* p = red + (size_t)(qg*64 + lane)*12;
    o0   += *(const f32x4*)&p[0];
    o1   += *(const f32x4*)&p[4];
    lacc += *(const f32x4*)&p[8];
    #pragma unroll
    for (int r = 0; r < 4; ++r) {
      const float invl = 1.0f / lacc[r];
      const int n = q0 + qg*16 + quad*4 + r;
      float* og = out + ((size_t)(b*NN + n))*DM + h*HD;
      og[n16]      = o0[r] * invl;
      og[16 + n16] = o1[r] * invl;
    }
  }
}

extern "C" void kernel_launch(void* const* d_in, const int* in_sizes, int n_in,
                              void* d_out, int out_size, void* d_ws, size_t ws_size,
                              hipStream_t stream) {
  const float* x      = (const float*)d_in[0];
  const float* adj    = (const float*)d_in[1];
  const int*   mask   = (const int*)d_in[2];
  const float* W      = (const float*)d_in[3];
  const float* bias   = (const float*)d_in[4];
  const float* shifts = (const float*)d_in[5];
  const float* widths = (const float*)d_in[6];
  const float* slwp   = (const float*)d_in[7];
  float* out = (float*)d_out;

  const size_t BHND = (size_t)BB*HH*NN*HD;          // 2,097,152
  const size_t WTN  = (size_t)TC*DM;                // 196,608
  __bf16* xbuf = (__bf16*)d_ws;                      // [8192,256] bf16
  __bf16* Wt   = xbuf + BHND;                        // [768,256] bf16
  __bf16* Qb   = Wt + WTN;                           // [B,H,N,32]
  __bf16* Kb   = Qb + BHND;
  __bf16* Vt   = Kb + BHND;

  precast<<<dim3(48 + (int)(BHND/4/256)), 256, 0, stream>>>(x, W, xbuf, Wt);
  qkv_gemm<<<dim3(TC/64, (BB*NN)/128), 256, 0, stream>>>(xbuf, Wt, bias, Qb, Kb, Vt);
  attn_kernel<<<dim3(BB*HH*32), 256, 0, stream>>>(Qb, Kb, Vt, adj, mask,
                                                  shifts, widths, slwp, out);
}